// Round 10
// baseline (224.491 us; speedup 1.0000x reference)
//
#include <hip/hip_runtime.h>
#include <math.h>

#define DIM 128
#define NHEADS 16
#define DPH 8
#define NATOMS 50000
#define NEDGES 400000
#define LN_EPS 1e-5f

typedef float f32x4 __attribute__((ext_vector_type(4)));
typedef short s16x8 __attribute__((ext_vector_type(8)));

static __device__ __forceinline__ unsigned short f2bf(float f) {
  unsigned u = __builtin_bit_cast(unsigned, f);
  unsigned r = (u + 0x7FFFu + ((u >> 16) & 1u)) >> 16;  // RNE
  return (unsigned short)r;
}
static __device__ __forceinline__ unsigned packbf(float lo, float hi) {
  return (unsigned)f2bf(lo) | ((unsigned)f2bf(hi) << 16);
}
static __device__ __forceinline__ float bflo(unsigned u) {
  return __builtin_bit_cast(float, u << 16);
}
static __device__ __forceinline__ float bfhi(unsigned u) {
  return __builtin_bit_cast(float, u & 0xffff0000u);
}

// fast GELU (tanh form): x * sigmoid(2*c0*(x + c1*x^3))
static __device__ __forceinline__ float gelu_fast(float x) {
  const float c0 = 0.7978845608028654f;
  const float c1 = 0.044715f;
  float u = c0 * (x + c1 * x * x * x);
  return __fdividef(x, 1.0f + __expf(-2.0f * u));
}

#define HIST_NB ((NEDGES + 255) / 256)  // 1563
#define SCAN_NB 196                     // ceil(50000/256)
#define LN_NB (NATOMS / 16)             // 3125

// ---------------------------------------------------------------------------
// k_convert: weight convert/transpose + cnt zeroing (replaces memset).
// ---------------------------------------------------------------------------
__global__ __launch_bounds__(256) void k_convert(
    const float* __restrict__ qkv_w, const float* __restrict__ out_w,
    unsigned short* __restrict__ wTq, unsigned short* __restrict__ wTo,
    int* __restrict__ cnt)
{
  const int idx = blockIdx.x * 256 + threadIdx.x;
  if (idx < NATOMS) cnt[idx] = 0;
  if (idx < 384 * 128) {
    const int c = idx >> 7, k = idx & 127;
    wTq[idx] = f2bf(qkv_w[k * 384 + c]);
  } else {
    const int i2 = idx - 384 * 128;
    const int c = i2 >> 7, k = i2 & 127;
    wTo[i2] = f2bf(out_w[k * 128 + c]);
  }
}

// ---------------------------------------------------------------------------
// K1: fused LayerNorm + QKV projection (MFMA) + (extra blocks) row histogram.
// ---------------------------------------------------------------------------
__global__ __launch_bounds__(256) void k_ln_qkv_hist(
    const float* __restrict__ node, const unsigned short* __restrict__ wTq,
    const float* __restrict__ bias, const float* __restrict__ g,
    const float* __restrict__ beta, unsigned* __restrict__ qb,
    unsigned* __restrict__ kvb, const int* __restrict__ row,
    int* __restrict__ cnt)
{
  if (blockIdx.x >= LN_NB) {
    const int e = (blockIdx.x - LN_NB) * 256 + threadIdx.x;
    if (e < NEDGES) atomicAdd(&cnt[row[e]], 1);
    return;
  }

  __shared__ float hpad[16][132];
  __shared__ float so[16][388];
  const int a0 = blockIdx.x * 16;
  const int tid = threadIdx.x;
  const int wid = tid >> 6;
  const int lane = tid & 63;

  for (int j = 0; j < 4; ++j) {
    const int a = wid * 4 + j;
    const float x0 = node[(size_t)(a0 + a) * DIM + lane];
    const float x1 = node[(size_t)(a0 + a) * DIM + 64 + lane];
    float s = x0 + x1;
    #pragma unroll
    for (int m = 1; m < 64; m <<= 1) s += __shfl_xor(s, m);
    const float mu = s * (1.0f / 128.0f);
    const float d0 = x0 - mu, d1 = x1 - mu;
    float v = d0 * d0 + d1 * d1;
    #pragma unroll
    for (int m = 1; m < 64; m <<= 1) v += __shfl_xor(v, m);
    const float rs = rsqrtf(v * (1.0f / 128.0f) + LN_EPS);
    hpad[a][lane]      = d0 * rs * g[lane]      + beta[lane];
    hpad[a][64 + lane] = d1 * rs * g[64 + lane] + beta[64 + lane];
  }
  __syncthreads();

  const int lrow = lane & 15;
  const int lquad = lane >> 4;
  const int colbase = wid * 96;

  s16x8 afrag[4];
  #pragma unroll
  for (int ks = 0; ks < 4; ++ks) {
    const int koff = ks * 32 + lquad * 8;
    const float4 p0 = *reinterpret_cast<const float4*>(&hpad[lrow][koff]);
    const float4 p1 = *reinterpret_cast<const float4*>(&hpad[lrow][koff + 4]);
    s16x8 af;
    af[0] = (short)f2bf(p0.x); af[1] = (short)f2bf(p0.y);
    af[2] = (short)f2bf(p0.z); af[3] = (short)f2bf(p0.w);
    af[4] = (short)f2bf(p1.x); af[5] = (short)f2bf(p1.y);
    af[6] = (short)f2bf(p1.z); af[7] = (short)f2bf(p1.w);
    afrag[ks] = af;
  }

  f32x4 acc[6];
  #pragma unroll
  for (int tt = 0; tt < 6; ++tt) acc[tt] = (f32x4){0.f, 0.f, 0.f, 0.f};

  #pragma unroll
  for (int tt = 0; tt < 6; ++tt) {
    const int cg = colbase + tt * 16 + lrow;
    #pragma unroll
    for (int ks = 0; ks < 4; ++ks) {
      const s16x8 bf = *reinterpret_cast<const s16x8*>(
          &wTq[(size_t)cg * 128 + ks * 32 + lquad * 8]);
      acc[tt] = __builtin_amdgcn_mfma_f32_16x16x32_bf16(afrag[ks], bf, acc[tt], 0, 0, 0);
    }
  }

  #pragma unroll
  for (int tt = 0; tt < 6; ++tt) {
    const int cg = colbase + tt * 16 + lrow;
    const float bz = bias[cg];
    const int hj = cg / 24;
    const int off = cg - hj * 24;
    int moff;
    if (off < 8)       moff = hj * 8 + off;
    else if (off < 16) moff = 128 + (hj * 8 + off - 8) * 2;
    else               moff = 128 + (hj * 8 + off - 16) * 2 + 1;
    #pragma unroll
    for (int r = 0; r < 4; ++r)
      so[lquad * 4 + r][moff] = acc[tt][r] + bz;
  }
  __syncthreads();

  #pragma unroll
  for (int kk = 0; kk < 4; ++kk) {
    const int i = tid + kk * 256;
    const int rowi = i >> 6;
    const int c2 = i & 63;
    qb[(size_t)(a0 + rowi) * 64 + c2] =
        packbf(so[rowi][2 * c2], so[rowi][2 * c2 + 1]);
  }
  #pragma unroll
  for (int kk = 0; kk < 8; ++kk) {
    const int i = tid + kk * 256;
    const int rowi = i >> 7;
    const int c = i & 127;
    kvb[(size_t)(a0 + rowi) * 128 + c] =
        packbf(so[rowi][128 + 2 * c], so[rowi][128 + 2 * c + 1]);
  }
}

// ---------------------------------------------------------------------------
// CSR build: per-block scan -> (offset-from-psum + apply) -> scatter desc
// ---------------------------------------------------------------------------
__global__ __launch_bounds__(256) void k_scan1(const int* __restrict__ cnt,
                                               int* __restrict__ locx,
                                               int* __restrict__ psum) {
  __shared__ int sh[256];
  const int tid = threadIdx.x;
  const int i = blockIdx.x * 256 + tid;
  const int v = (i < NATOMS) ? cnt[i] : 0;
  sh[tid] = v;
  __syncthreads();
  #pragma unroll
  for (int off = 1; off < 256; off <<= 1) {
    const int cur = sh[tid];
    const int add = (tid >= off) ? sh[tid - off] : 0;
    __syncthreads();
    sh[tid] = cur + add;
    __syncthreads();
  }
  if (i < NATOMS) locx[i] = sh[tid] - v;  // exclusive
  if (tid == 255) psum[blockIdx.x] = sh[255];
}

__global__ __launch_bounds__(256) void k_scan23(const int* __restrict__ psum,
                                                const int* __restrict__ locx,
                                                int* __restrict__ base,
                                                int* __restrict__ cursor) {
  __shared__ int ws[4];
  const int bid = blockIdx.x;
  const int tid = threadIdx.x;
  const int lane = tid & 63;
  const int wid = tid >> 6;

  int s = (tid < bid) ? psum[tid] : 0;  // bid <= 195 < 256
  #pragma unroll
  for (int m = 1; m < 64; m <<= 1) s += __shfl_xor(s, m);
  if (lane == 0) ws[wid] = s;
  __syncthreads();
  const int off = ws[0] + ws[1] + ws[2] + ws[3];

  const int i = bid * 256 + tid;
  if (i < NATOMS) {
    const int b = locx[i] + off;
    base[i] = b;
    cursor[i] = b;
  }
  if (bid == 0 && tid == 0) base[NATOMS] = NEDGES;
}

// Scatter edge descriptors into CSR order: descA[p]={e,col,radial,ev0},
// descB[p]={ev1,ev2}.
__global__ __launch_bounds__(256) void k_scatter(
    const int* __restrict__ row, const int* __restrict__ col,
    const float* __restrict__ radial, const float* __restrict__ evec,
    int* __restrict__ cursor, int4* __restrict__ descA,
    float2* __restrict__ descB)
{
  const int e = blockIdx.x * 256 + threadIdx.x;
  if (e < NEDGES) {
    const int p = atomicAdd(&cursor[row[e]], 1);
    descA[p] = make_int4(e, col[e], __float_as_int(radial[e]),
                         __float_as_int(evec[(size_t)e * 3]));
    descB[p] = make_float2(evec[(size_t)e * 3 + 1], evec[(size_t)e * 3 + 2]);
  }
}

// ---------------------------------------------------------------------------
// K2: edge accumulation, head-per-lane geometry.
// 16 lanes per atom, 8 channels (one head) per lane -> q.k dot is fully
// lane-local (8 FMA, zero shuffles); one wave runs 4 atoms' edge streams
// concurrently. A/B double-buffered kv/ef (8 edges in flight per wave);
// descriptors affine in p, loaded 2 edges ahead. Tails masked via payload.
// FIX vs R9: uniform break between COMPUTE(A) and COMPUTE(B) so a stale B
// buffer is never re-consumed when md is odd (edge double-count bug).
// ---------------------------------------------------------------------------
__global__ __launch_bounds__(256) void k_edge_csr(
    const uint4* __restrict__ qb4, const uint4* __restrict__ kvb4,
    const float4* __restrict__ ef4, const int4* __restrict__ descA,
    const float2* __restrict__ descB, const int* __restrict__ base,
    uint4* __restrict__ mfeat4, float* __restrict__ outvec)
{
  const int tid = threadIdx.x;
  const int lane = tid & 63;
  const int sub = lane >> 4;    // atom within wave (0..3)
  const int h = lane & 15;      // head
  const int a = (blockIdx.x * 4 + (tid >> 6)) * 4 + sub;

  const int pBeg = base[a];
  const int pEnd = base[a + 1];
  const int deg = pEnd - pBeg;

  // wave-max degree (uniform loop bound)
  int md = deg;
  #pragma unroll
  for (int m = 1; m < 64; m <<= 1) {
    const int o = __shfl_xor(md, m);
    md = md > o ? md : o;
  }

  float fa[8], vv0[8], vv1[8], vv2[8];
  #pragma unroll
  for (int i = 0; i < 8; ++i) { fa[i] = 0.f; vv0[i] = 0.f; vv1[i] = 0.f; vv2[i] = 0.f; }

  if (md > 0) {
    const int hi = (deg > 0) ? (pEnd - 1) : 0;  // clamp target (valid memory)

    // q: 8 channels of head h (loop-invariant)
    const uint4 qa = qb4[(size_t)a * 16 + h];
    float q[8];
    q[0] = bflo(qa.x); q[1] = bfhi(qa.x);
    q[2] = bflo(qa.y); q[3] = bfhi(qa.y);
    q[4] = bflo(qa.z); q[5] = bfhi(qa.z);
    q[6] = bflo(qa.w); q[7] = bfhi(qa.w);

    uint4 kv0A, kv1A, kv0B, kv1B;
    float4 ef0A, ef1A, ef0B, ef1B;
    int4 dA, dB;
    float2 bA, bB;
    float rA, xA, yA, zA, rB, xB, yB, zB;

#define LDESC(D, BB, IT) do {                                               \
    int pc_ = pBeg + (IT);                                                  \
    pc_ = (pc_ <= hi) ? pc_ : hi;                                           \
    D = descA[pc_];                                                         \
    BB = descB[pc_];                                                        \
  } while (0)

    // STAGE: copy payload (masked) from desc regs, issue kv/ef loads.
#define STAGE(S, IT) do {                                                   \
    const float m_ = ((IT) < deg) ? 1.f : 0.f;                              \
    r##S = __int_as_float(d##S.z) * m_;                                     \
    x##S = __int_as_float(d##S.w) * m_;                                     \
    y##S = b##S.x * m_;                                                     \
    z##S = b##S.y * m_;                                                     \
    const size_t cb_ = (size_t)(unsigned)d##S.y * 32 + 2 * h;               \
    const size_t eb_ = (size_t)(unsigned)d##S.x * 32 + 2 * h;               \
    kv0##S = kvb4[cb_];                                                     \
    kv1##S = kvb4[cb_ + 1];                                                 \
    ef0##S = ef4[eb_];                                                      \
    ef1##S = ef4[eb_ + 1];                                                  \
  } while (0)

#define COMPUTE(S) do {                                                     \
    float k_[8], v_[8], e_[8];                                              \
    k_[0] = bflo(kv0##S.x); v_[0] = bfhi(kv0##S.x);                         \
    k_[1] = bflo(kv0##S.y); v_[1] = bfhi(kv0##S.y);                         \
    k_[2] = bflo(kv0##S.z); v_[2] = bfhi(kv0##S.z);                         \
    k_[3] = bflo(kv0##S.w); v_[3] = bfhi(kv0##S.w);                         \
    k_[4] = bflo(kv1##S.x); v_[4] = bfhi(kv1##S.x);                         \
    k_[5] = bflo(kv1##S.y); v_[5] = bfhi(kv1##S.y);                         \
    k_[6] = bflo(kv1##S.z); v_[6] = bfhi(kv1##S.z);                         \
    k_[7] = bflo(kv1##S.w); v_[7] = bfhi(kv1##S.w);                         \
    e_[0] = ef0##S.x; e_[1] = ef0##S.y; e_[2] = ef0##S.z; e_[3] = ef0##S.w; \
    e_[4] = ef1##S.x; e_[5] = ef1##S.y; e_[6] = ef1##S.z; e_[7] = ef1##S.w; \
    float p_ = q[0] * k_[0];                                                \
    p_ = fmaf(q[1], k_[1], p_); p_ = fmaf(q[2], k_[2], p_);                 \
    p_ = fmaf(q[3], k_[3], p_); p_ = fmaf(q[4], k_[4], p_);                 \
    p_ = fmaf(q[5], k_[5], p_); p_ = fmaf(q[6], k_[6], p_);                 \
    p_ = fmaf(q[7], k_[7], p_);                                             \
    const float at_ = gelu_fast(p_) * r##S;                                 \
    _Pragma("unroll")                                                       \
    for (int i_ = 0; i_ < 8; ++i_) {                                        \
      fa[i_]  = fmaf(v_[i_] * e_[i_], at_, fa[i_]);                         \
      vv0[i_] = fmaf(v_[i_], x##S, vv0[i_]);                                \
      vv1[i_] = fmaf(v_[i_], y##S, vv1[i_]);                                \
      vv2[i_] = fmaf(v_[i_], z##S, vv2[i_]);                                \
    }                                                                       \
  } while (0)

    // prologue: stage edges 0,1; desc in regs for 2,3
    LDESC(dA, bA, 0);
    LDESC(dB, bB, 1);
    STAGE(A, 0);
    STAGE(B, 1);
    LDESC(dA, bA, 2);
    LDESC(dB, bB, 3);

    for (int it = 0; it < md; it += 2) {
      COMPUTE(A);
      if (it + 2 < md) { STAGE(A, it + 2); LDESC(dA, bA, it + 4); }
      if (it + 1 >= md) break;  // B buffer not valid past md (uniform branch)
      COMPUTE(B);
      if (it + 3 < md) { STAGE(B, it + 3); LDESC(dB, bB, it + 5); }
    }

#undef LDESC
#undef STAGE
#undef COMPUTE
  }

  // flush: this lane owns head h of atom a
  mfeat4[(size_t)a * 16 + h] =
      make_uint4(packbf(fa[0], fa[1]), packbf(fa[2], fa[3]),
                 packbf(fa[4], fa[5]), packbf(fa[6], fa[7]));
  float* ov = outvec + (size_t)a * 384 + 8 * h;
  *reinterpret_cast<float4*>(ov)       = make_float4(vv0[0], vv0[1], vv0[2], vv0[3]);
  *reinterpret_cast<float4*>(ov + 4)   = make_float4(vv0[4], vv0[5], vv0[6], vv0[7]);
  *reinterpret_cast<float4*>(ov + 128) = make_float4(vv1[0], vv1[1], vv1[2], vv1[3]);
  *reinterpret_cast<float4*>(ov + 132) = make_float4(vv1[4], vv1[5], vv1[6], vv1[7]);
  *reinterpret_cast<float4*>(ov + 256) = make_float4(vv2[0], vv2[1], vv2[2], vv2[3]);
  *reinterpret_cast<float4*>(ov + 260) = make_float4(vv2[4], vv2[5], vv2[6], vv2[7]);
}

// ---------------------------------------------------------------------------
// K3: delta_node_feat = m_feat(bf16) @ out_wT(bf16) + out_b via MFMA,
// LDS-staged coalesced epilogue.
// ---------------------------------------------------------------------------
__global__ __launch_bounds__(256) void k_out(
    const unsigned short* __restrict__ mfeatb,
    const unsigned short* __restrict__ wTo,
    const float* __restrict__ bias, float* __restrict__ out)
{
  __shared__ float so[16][132];
  const int a0 = blockIdx.x * 16;
  const int tid = threadIdx.x;
  const int wid = tid >> 6;
  const int lane = tid & 63;
  const int lrow = lane & 15;
  const int lquad = lane >> 4;

  s16x8 afrag[4];
  #pragma unroll
  for (int ks = 0; ks < 4; ++ks)
    afrag[ks] = *reinterpret_cast<const s16x8*>(
        &mfeatb[(size_t)(a0 + lrow) * 128 + ks * 32 + lquad * 8]);

  f32x4 acc[2];
  acc[0] = (f32x4){0.f, 0.f, 0.f, 0.f};
  acc[1] = (f32x4){0.f, 0.f, 0.f, 0.f};

  #pragma unroll
  for (int tt = 0; tt < 2; ++tt) {
    const int cg = wid * 32 + tt * 16 + lrow;
    #pragma unroll
    for (int ks = 0; ks < 4; ++ks) {
      const s16x8 bf = *reinterpret_cast<const s16x8*>(
          &wTo[(size_t)cg * 128 + ks * 32 + lquad * 8]);
      acc[tt] = __builtin_amdgcn_mfma_f32_16x16x32_bf16(afrag[ks], bf, acc[tt], 0, 0, 0);
    }
  }

  #pragma unroll
  for (int tt = 0; tt < 2; ++tt) {
    const int cg = wid * 32 + tt * 16 + lrow;
    const float bz = bias[cg];
    #pragma unroll
    for (int r = 0; r < 4; ++r)
      so[lquad * 4 + r][cg] = acc[tt][r] + bz;
  }
  __syncthreads();

  f32x4* out4 = (f32x4*)out;
  #pragma unroll
  for (int kk = 0; kk < 2; ++kk) {
    const int idx4 = tid + kk * 256;
    const int rowi = idx4 >> 5;
    const int c4 = idx4 & 31;
    out4[(size_t)(a0 + rowi) * 32 + c4] =
        *reinterpret_cast<const f32x4*>(&so[rowi][c4 * 4]);
  }
}

extern "C" void kernel_launch(void* const* d_in, const int* in_sizes, int n_in,
                              void* d_out, int out_size, void* d_ws, size_t ws_size,
                              hipStream_t stream) {
  const float* node_feat = (const float*)d_in[0];
  const float* edge_feat = (const float*)d_in[1];
  const float* edge_vec  = (const float*)d_in[2];
  const float* radial    = (const float*)d_in[3];
  const float* qkv_w     = (const float*)d_in[4];
  const float* qkv_b     = (const float*)d_in[5];
  const float* out_w     = (const float*)d_in[6];
  const float* out_b     = (const float*)d_in[7];
  const float* ln_g      = (const float*)d_in[8];
  const float* ln_b      = (const float*)d_in[9];
  const int*   row       = (const int*)d_in[10];
  const int*   col       = (const int*)d_in[11];

  float* out      = (float*)d_out;
  float* out_feat = out;                           // [50000][128]
  float* out_vec  = out + (size_t)NATOMS * DIM;    // [50000][3][128]

  // workspace layout (16B-aligned sections)
  unsigned* qb  = (unsigned*)d_ws;                              // 50000*64 u32
  unsigned* kvb = qb + (size_t)NATOMS * 64;                     // 50000*128 u32
  unsigned short* mfeatb = (unsigned short*)(kvb + (size_t)NATOMS * 128); // 50000*128 bf16
  unsigned short* wTq = mfeatb + (size_t)NATOMS * 128;          // 384*128 bf16
  unsigned short* wTo = wTq + 384 * 128;                        // 128*128 bf16
  int4* descA  = (int4*)(wTo + 128 * 128);                      // 400000 int4
  float2* descB = (float2*)(descA + NEDGES);                    // 400000 float2
  int* cnt    = (int*)(descB + NEDGES);                         // 50000
  int* base   = cnt + NATOMS;                                   // 50001
  int* cursor = base + NATOMS + 1;                              // 50000
  int* locx   = cursor + NATOMS;                                // 50000
  int* psum   = locx + NATOMS;                                  // 256

  k_convert<<<256, 256, 0, stream>>>(qkv_w, out_w, wTq, wTo, cnt);

  k_ln_qkv_hist<<<LN_NB + HIST_NB, 256, 0, stream>>>(
      node_feat, wTq, qkv_b, ln_g, ln_b, qb, kvb, row, cnt);

  k_scan1<<<SCAN_NB, 256, 0, stream>>>(cnt, locx, psum);
  k_scan23<<<SCAN_NB, 256, 0, stream>>>(psum, locx, base, cursor);
  k_scatter<<<HIST_NB, 256, 0, stream>>>(row, col, radial, edge_vec, cursor,
                                         descA, descB);

  k_edge_csr<<<NATOMS / 16, 256, 0, stream>>>(
      (const uint4*)qb, (const uint4*)kvb, (const float4*)edge_feat,
      descA, descB, base, (uint4*)mfeatb, out_vec);

  k_out<<<NATOMS / 16, 256, 0, stream>>>(mfeatb, wTo, out_b, out_feat);
}

// Round 11
// 217.850 us; speedup vs baseline: 1.0305x; 1.0305x over previous
//
#include <hip/hip_runtime.h>
#include <math.h>

#define DIM 128
#define NHEADS 16
#define DPH 8
#define NATOMS 50000
#define NEDGES 400000
#define LN_EPS 1e-5f

typedef float f32x4 __attribute__((ext_vector_type(4)));
typedef short s16x8 __attribute__((ext_vector_type(8)));

static __device__ __forceinline__ unsigned short f2bf(float f) {
  unsigned u = __builtin_bit_cast(unsigned, f);
  unsigned r = (u + 0x7FFFu + ((u >> 16) & 1u)) >> 16;  // RNE
  return (unsigned short)r;
}
static __device__ __forceinline__ unsigned packbf(float lo, float hi) {
  return (unsigned)f2bf(lo) | ((unsigned)f2bf(hi) << 16);
}
static __device__ __forceinline__ float bflo(unsigned u) {
  return __builtin_bit_cast(float, u << 16);
}
static __device__ __forceinline__ float bfhi(unsigned u) {
  return __builtin_bit_cast(float, u & 0xffff0000u);
}

// fast GELU (tanh form): x * sigmoid(2*c0*(x + c1*x^3))
static __device__ __forceinline__ float gelu_fast(float x) {
  const float c0 = 0.7978845608028654f;
  const float c1 = 0.044715f;
  float u = c0 * (x + c1 * x * x * x);
  return __fdividef(x, 1.0f + __expf(-2.0f * u));
}

#define HIST_NB ((NEDGES + 255) / 256)  // 1563
#define SCAN_NB 196                     // ceil(50000/256)
#define LN_NB (NATOMS / 16)             // 3125

// ---------------------------------------------------------------------------
// k_convert: weight convert/transpose + cnt zeroing (replaces memset).
// ---------------------------------------------------------------------------
__global__ __launch_bounds__(256) void k_convert(
    const float* __restrict__ qkv_w, const float* __restrict__ out_w,
    unsigned short* __restrict__ wTq, unsigned short* __restrict__ wTo,
    int* __restrict__ cnt)
{
  const int idx = blockIdx.x * 256 + threadIdx.x;
  if (idx < NATOMS) cnt[idx] = 0;
  if (idx < 384 * 128) {
    const int c = idx >> 7, k = idx & 127;
    wTq[idx] = f2bf(qkv_w[k * 384 + c]);
  } else {
    const int i2 = idx - 384 * 128;
    const int c = i2 >> 7, k = i2 & 127;
    wTo[i2] = f2bf(out_w[k * 128 + c]);
  }
}

// ---------------------------------------------------------------------------
// K1: fused LayerNorm + QKV projection (MFMA) + (extra blocks) row histogram.
// ---------------------------------------------------------------------------
__global__ __launch_bounds__(256) void k_ln_qkv_hist(
    const float* __restrict__ node, const unsigned short* __restrict__ wTq,
    const float* __restrict__ bias, const float* __restrict__ g,
    const float* __restrict__ beta, unsigned* __restrict__ qb,
    unsigned* __restrict__ kvb, const int* __restrict__ row,
    int* __restrict__ cnt)
{
  if (blockIdx.x >= LN_NB) {
    const int e = (blockIdx.x - LN_NB) * 256 + threadIdx.x;
    if (e < NEDGES) atomicAdd(&cnt[row[e]], 1);
    return;
  }

  __shared__ float hpad[16][132];
  __shared__ float so[16][388];
  const int a0 = blockIdx.x * 16;
  const int tid = threadIdx.x;
  const int wid = tid >> 6;
  const int lane = tid & 63;

  for (int j = 0; j < 4; ++j) {
    const int a = wid * 4 + j;
    const float x0 = node[(size_t)(a0 + a) * DIM + lane];
    const float x1 = node[(size_t)(a0 + a) * DIM + 64 + lane];
    float s = x0 + x1;
    #pragma unroll
    for (int m = 1; m < 64; m <<= 1) s += __shfl_xor(s, m);
    const float mu = s * (1.0f / 128.0f);
    const float d0 = x0 - mu, d1 = x1 - mu;
    float v = d0 * d0 + d1 * d1;
    #pragma unroll
    for (int m = 1; m < 64; m <<= 1) v += __shfl_xor(v, m);
    const float rs = rsqrtf(v * (1.0f / 128.0f) + LN_EPS);
    hpad[a][lane]      = d0 * rs * g[lane]      + beta[lane];
    hpad[a][64 + lane] = d1 * rs * g[64 + lane] + beta[64 + lane];
  }
  __syncthreads();

  const int lrow = lane & 15;
  const int lquad = lane >> 4;
  const int colbase = wid * 96;

  s16x8 afrag[4];
  #pragma unroll
  for (int ks = 0; ks < 4; ++ks) {
    const int koff = ks * 32 + lquad * 8;
    const float4 p0 = *reinterpret_cast<const float4*>(&hpad[lrow][koff]);
    const float4 p1 = *reinterpret_cast<const float4*>(&hpad[lrow][koff + 4]);
    s16x8 af;
    af[0] = (short)f2bf(p0.x); af[1] = (short)f2bf(p0.y);
    af[2] = (short)f2bf(p0.z); af[3] = (short)f2bf(p0.w);
    af[4] = (short)f2bf(p1.x); af[5] = (short)f2bf(p1.y);
    af[6] = (short)f2bf(p1.z); af[7] = (short)f2bf(p1.w);
    afrag[ks] = af;
  }

  f32x4 acc[6];
  #pragma unroll
  for (int tt = 0; tt < 6; ++tt) acc[tt] = (f32x4){0.f, 0.f, 0.f, 0.f};

  #pragma unroll
  for (int tt = 0; tt < 6; ++tt) {
    const int cg = colbase + tt * 16 + lrow;
    #pragma unroll
    for (int ks = 0; ks < 4; ++ks) {
      const s16x8 bf = *reinterpret_cast<const s16x8*>(
          &wTq[(size_t)cg * 128 + ks * 32 + lquad * 8]);
      acc[tt] = __builtin_amdgcn_mfma_f32_16x16x32_bf16(afrag[ks], bf, acc[tt], 0, 0, 0);
    }
  }

  #pragma unroll
  for (int tt = 0; tt < 6; ++tt) {
    const int cg = colbase + tt * 16 + lrow;
    const float bz = bias[cg];
    const int hj = cg / 24;
    const int off = cg - hj * 24;
    int moff;
    if (off < 8)       moff = hj * 8 + off;
    else if (off < 16) moff = 128 + (hj * 8 + off - 8) * 2;
    else               moff = 128 + (hj * 8 + off - 16) * 2 + 1;
    #pragma unroll
    for (int r = 0; r < 4; ++r)
      so[lquad * 4 + r][moff] = acc[tt][r] + bz;
  }
  __syncthreads();

  #pragma unroll
  for (int kk = 0; kk < 4; ++kk) {
    const int i = tid + kk * 256;
    const int rowi = i >> 6;
    const int c2 = i & 63;
    qb[(size_t)(a0 + rowi) * 64 + c2] =
        packbf(so[rowi][2 * c2], so[rowi][2 * c2 + 1]);
  }
  #pragma unroll
  for (int kk = 0; kk < 8; ++kk) {
    const int i = tid + kk * 256;
    const int rowi = i >> 7;
    const int c = i & 127;
    kvb[(size_t)(a0 + rowi) * 128 + c] =
        packbf(so[rowi][128 + 2 * c], so[rowi][128 + 2 * c + 1]);
  }
}

// ---------------------------------------------------------------------------
// CSR build: per-block scan -> (offset-from-psum + apply) -> scatter desc
// ---------------------------------------------------------------------------
__global__ __launch_bounds__(256) void k_scan1(const int* __restrict__ cnt,
                                               int* __restrict__ locx,
                                               int* __restrict__ psum) {
  __shared__ int sh[256];
  const int tid = threadIdx.x;
  const int i = blockIdx.x * 256 + tid;
  const int v = (i < NATOMS) ? cnt[i] : 0;
  sh[tid] = v;
  __syncthreads();
  #pragma unroll
  for (int off = 1; off < 256; off <<= 1) {
    const int cur = sh[tid];
    const int add = (tid >= off) ? sh[tid - off] : 0;
    __syncthreads();
    sh[tid] = cur + add;
    __syncthreads();
  }
  if (i < NATOMS) locx[i] = sh[tid] - v;  // exclusive
  if (tid == 255) psum[blockIdx.x] = sh[255];
}

__global__ __launch_bounds__(256) void k_scan23(const int* __restrict__ psum,
                                                const int* __restrict__ locx,
                                                int* __restrict__ base,
                                                int* __restrict__ cursor) {
  __shared__ int ws[4];
  const int bid = blockIdx.x;
  const int tid = threadIdx.x;
  const int lane = tid & 63;
  const int wid = tid >> 6;

  int s = (tid < bid) ? psum[tid] : 0;  // bid <= 195 < 256
  #pragma unroll
  for (int m = 1; m < 64; m <<= 1) s += __shfl_xor(s, m);
  if (lane == 0) ws[wid] = s;
  __syncthreads();
  const int off = ws[0] + ws[1] + ws[2] + ws[3];

  const int i = bid * 256 + tid;
  if (i < NATOMS) {
    const int b = locx[i] + off;
    base[i] = b;
    cursor[i] = b;
  }
  if (bid == 0 && tid == 0) base[NATOMS] = NEDGES;
}

// Scatter edge descriptors into CSR order: descA[p]={e,col,radial,ev0},
// descB[p]={ev1,ev2}.
__global__ __launch_bounds__(256) void k_scatter(
    const int* __restrict__ row, const int* __restrict__ col,
    const float* __restrict__ radial, const float* __restrict__ evec,
    int* __restrict__ cursor, int4* __restrict__ descA,
    float2* __restrict__ descB)
{
  const int e = blockIdx.x * 256 + threadIdx.x;
  if (e < NEDGES) {
    const int p = atomicAdd(&cursor[row[e]], 1);
    descA[p] = make_int4(e, col[e], __float_as_int(radial[e]),
                         __float_as_int(evec[(size_t)e * 3]));
    descB[p] = make_float2(evec[(size_t)e * 3 + 1], evec[(size_t)e * 3 + 2]);
  }
}

// ---------------------------------------------------------------------------
// K2: edge accumulation. 1 atom per wave (uniform degree loop), 2 ch/lane,
// 4 waves/block. Triple-buffered quads A/B/C: 12 edges in flight per wave,
// two COMPUTE phases (~480 cyc) between a quad's load-issue and its use.
// Descriptors + payload live on the scalar path (uniform indices -> s_load);
// tail edges are masked by zeroing the PAYLOAD via scalar selects (no
// per-edge VALU masks needed). No atomics.
// ---------------------------------------------------------------------------
__global__ __launch_bounds__(256) void k_edge_csr(
    const unsigned* __restrict__ qb, const uint2* __restrict__ kvb,
    const float2* __restrict__ ef2, const int4* __restrict__ descA,
    const float2* __restrict__ descB, const int* __restrict__ base,
    unsigned* __restrict__ mfeatw, float* __restrict__ outvec)
{
  const int tid = threadIdx.x;
  const int a = blockIdx.x * 4 + (tid >> 6);
  const int t = tid & 63;

  const int pBeg = __builtin_amdgcn_readfirstlane(base[a]);
  const int pEnd = __builtin_amdgcn_readfirstlane(base[a + 1]);
  const int deg = pEnd - pBeg;

  float f0 = 0.f, f1 = 0.f;
  float va0 = 0.f, va1 = 0.f, vb0 = 0.f, vb1 = 0.f, vc0 = 0.f, vc1 = 0.f;

  if (deg > 0) {
    const unsigned qp = qb[(size_t)a * 64 + t];
    const float q0 = bflo(qp), q1 = bfhi(qp);
    const int pLast = pEnd - 1;

    int4 u0, u1, u2, u3;
    float2 w0, w1, w2, w3;
    uint2 kvA0, kvA1, kvA2, kvA3, kvB0, kvB1, kvB2, kvB3,
          kvC0, kvC1, kvC2, kvC3;
    float2 efA0, efA1, efA2, efA3, efB0, efB1, efB2, efB3,
           efC0, efC1, efC2, efC3;
    float rA0, rA1, rA2, rA3, xA0, xA1, xA2, xA3,
          yA0, yA1, yA2, yA3, zA0, zA1, zA2, zA3;
    float rB0, rB1, rB2, rB3, xB0, xB1, xB2, xB3,
          yB0, yB1, yB2, yB3, zB0, zB1, zB2, zB3;
    float rC0, rC1, rC2, rC3, xC0, xC1, xC2, xC3,
          yC0, yC1, yC2, yC3, zC0, zC1, zC2, zC3;

#define LDESC(P) do {                                                       \
    const int j0_ = ((P)     <= pLast) ? (P)     : pLast;                   \
    const int j1_ = ((P) + 1 <= pLast) ? (P) + 1 : pLast;                   \
    const int j2_ = ((P) + 2 <= pLast) ? (P) + 2 : pLast;                   \
    const int j3_ = ((P) + 3 <= pLast) ? (P) + 3 : pLast;                   \
    u0 = descA[j0_]; w0 = descB[j0_];                                       \
    u1 = descA[j1_]; w1 = descB[j1_];                                       \
    u2 = descA[j2_]; w2 = descB[j2_];                                       \
    u3 = descA[j3_]; w3 = descB[j3_];                                       \
  } while (0)

    // STAGE: select payload (zero past-tail) + issue kv/ef loads.
#define STAGE(S, IT) do {                                                   \
    const bool g0_ = (IT)     < deg, g1_ = (IT) + 1 < deg;                  \
    const bool g2_ = (IT) + 2 < deg, g3_ = (IT) + 3 < deg;                  \
    r##S##0 = g0_ ? __int_as_float(u0.z) : 0.f;                             \
    x##S##0 = g0_ ? __int_as_float(u0.w) : 0.f;                             \
    y##S##0 = g0_ ? w0.x : 0.f;  z##S##0 = g0_ ? w0.y : 0.f;                \
    r##S##1 = g1_ ? __int_as_float(u1.z) : 0.f;                             \
    x##S##1 = g1_ ? __int_as_float(u1.w) : 0.f;                             \
    y##S##1 = g1_ ? w1.x : 0.f;  z##S##1 = g1_ ? w1.y : 0.f;                \
    r##S##2 = g2_ ? __int_as_float(u2.z) : 0.f;                             \
    x##S##2 = g2_ ? __int_as_float(u2.w) : 0.f;                             \
    y##S##2 = g2_ ? w2.x : 0.f;  z##S##2 = g2_ ? w2.y : 0.f;                \
    r##S##3 = g3_ ? __int_as_float(u3.z) : 0.f;                             \
    x##S##3 = g3_ ? __int_as_float(u3.w) : 0.f;                             \
    y##S##3 = g3_ ? w3.x : 0.f;  z##S##3 = g3_ ? w3.y : 0.f;                \
    kv##S##0 = kvb[(size_t)(unsigned)u0.y * 64 + t];                        \
    ef##S##0 = ef2[(size_t)(unsigned)u0.x * 64 + t];                        \
    kv##S##1 = kvb[(size_t)(unsigned)u1.y * 64 + t];                        \
    ef##S##1 = ef2[(size_t)(unsigned)u1.x * 64 + t];                        \
    kv##S##2 = kvb[(size_t)(unsigned)u2.y * 64 + t];                        \
    ef##S##2 = ef2[(size_t)(unsigned)u2.x * 64 + t];                        \
    kv##S##3 = kvb[(size_t)(unsigned)u3.y * 64 + t];                        \
    ef##S##3 = ef2[(size_t)(unsigned)u3.x * 64 + t];                        \
  } while (0)

    // One edge: payload==0 for past-tail edges zeroes every contribution.
#define EDGE1(KV, EF, RR, XX, YY, ZZ) do {                                  \
    const float kx0_ = bflo(KV.x), kx1_ = bflo(KV.y);                       \
    const float vx0_ = bfhi(KV.x), vx1_ = bfhi(KV.y);                       \
    float pd_ = q0 * kx0_; pd_ = fmaf(q1, kx1_, pd_);                       \
    pd_ += __shfl_xor(pd_, 1); pd_ += __shfl_xor(pd_, 2);                   \
    const float at_ = gelu_fast(pd_) * (RR);                                \
    f0 = fmaf(vx0_ * EF.x, at_, f0);                                        \
    f1 = fmaf(vx1_ * EF.y, at_, f1);                                        \
    va0 = fmaf(vx0_, (XX), va0); va1 = fmaf(vx1_, (XX), va1);               \
    vb0 = fmaf(vx0_, (YY), vb0); vb1 = fmaf(vx1_, (YY), vb1);               \
    vc0 = fmaf(vx0_, (ZZ), vc0); vc1 = fmaf(vx1_, (ZZ), vc1);               \
  } while (0)

#define COMPUTE(S) do {                                                     \
    EDGE1(kv##S##0, ef##S##0, r##S##0, x##S##0, y##S##0, z##S##0);          \
    EDGE1(kv##S##1, ef##S##1, r##S##1, x##S##1, y##S##1, z##S##1);          \
    EDGE1(kv##S##2, ef##S##2, r##S##2, x##S##2, y##S##2, z##S##2);          \
    EDGE1(kv##S##3, ef##S##3, r##S##3, x##S##3, y##S##3, z##S##3);          \
  } while (0)

    // prologue: fill A,B,C (quads 0,4,8); desc regs hold quad 12
    LDESC(pBeg);      STAGE(A, 0);
    LDESC(pBeg + 4);  STAGE(B, 4);
    LDESC(pBeg + 8);  STAGE(C, 8);
    LDESC(pBeg + 12);

    int it = 0;
    while (true) {
      COMPUTE(A);                                   // quad it
      if (it + 4 >= deg) break;
      STAGE(A, it + 12); LDESC(pBeg + it + 16);     // refill A with quad it+12
      COMPUTE(B);                                   // quad it+4
      if (it + 8 >= deg) break;
      STAGE(B, it + 16); LDESC(pBeg + it + 20);
      COMPUTE(C);                                   // quad it+8
      if (it + 12 >= deg) break;
      STAGE(C, it + 20); LDESC(pBeg + it + 24);
      it += 12;
    }

#undef LDESC
#undef STAGE
#undef EDGE1
#undef COMPUTE
  }

  mfeatw[(size_t)a * 64 + t] = packbf(f0, f1);
  float* ov = outvec + (size_t)a * 384 + 2 * t;
  *reinterpret_cast<float2*>(ov)       = make_float2(va0, va1);
  *reinterpret_cast<float2*>(ov + 128) = make_float2(vb0, vb1);
  *reinterpret_cast<float2*>(ov + 256) = make_float2(vc0, vc1);
}

// ---------------------------------------------------------------------------
// K3: delta_node_feat = m_feat(bf16) @ out_wT(bf16) + out_b via MFMA,
// LDS-staged coalesced epilogue.
// ---------------------------------------------------------------------------
__global__ __launch_bounds__(256) void k_out(
    const unsigned short* __restrict__ mfeatb,
    const unsigned short* __restrict__ wTo,
    const float* __restrict__ bias, float* __restrict__ out)
{
  __shared__ float so[16][132];
  const int a0 = blockIdx.x * 16;
  const int tid = threadIdx.x;
  const int wid = tid >> 6;
  const int lane = tid & 63;
  const int lrow = lane & 15;
  const int lquad = lane >> 4;

  s16x8 afrag[4];
  #pragma unroll
  for (int ks = 0; ks < 4; ++ks)
    afrag[ks] = *reinterpret_cast<const s16x8*>(
        &mfeatb[(size_t)(a0 + lrow) * 128 + ks * 32 + lquad * 8]);

  f32x4 acc[2];
  acc[0] = (f32x4){0.f, 0.f, 0.f, 0.f};
  acc[1] = (f32x4){0.f, 0.f, 0.f, 0.f};

  #pragma unroll
  for (int tt = 0; tt < 2; ++tt) {
    const int cg = wid * 32 + tt * 16 + lrow;
    #pragma unroll
    for (int ks = 0; ks < 4; ++ks) {
      const s16x8 bf = *reinterpret_cast<const s16x8*>(
          &wTo[(size_t)cg * 128 + ks * 32 + lquad * 8]);
      acc[tt] = __builtin_amdgcn_mfma_f32_16x16x32_bf16(afrag[ks], bf, acc[tt], 0, 0, 0);
    }
  }

  #pragma unroll
  for (int tt = 0; tt < 2; ++tt) {
    const int cg = wid * 32 + tt * 16 + lrow;
    const float bz = bias[cg];
    #pragma unroll
    for (int r = 0; r < 4; ++r)
      so[lquad * 4 + r][cg] = acc[tt][r] + bz;
  }
  __syncthreads();

  f32x4* out4 = (f32x4*)out;
  #pragma unroll
  for (int kk = 0; kk < 2; ++kk) {
    const int idx4 = tid + kk * 256;
    const int rowi = idx4 >> 5;
    const int c4 = idx4 & 31;
    out4[(size_t)(a0 + rowi) * 32 + c4] =
        *reinterpret_cast<const f32x4*>(&so[rowi][c4 * 4]);
  }
}

extern "C" void kernel_launch(void* const* d_in, const int* in_sizes, int n_in,
                              void* d_out, int out_size, void* d_ws, size_t ws_size,
                              hipStream_t stream) {
  const float* node_feat = (const float*)d_in[0];
  const float* edge_feat = (const float*)d_in[1];
  const float* edge_vec  = (const float*)d_in[2];
  const float* radial    = (const float*)d_in[3];
  const float* qkv_w     = (const float*)d_in[4];
  const float* qkv_b     = (const float*)d_in[5];
  const float* out_w     = (const float*)d_in[6];
  const float* out_b     = (const float*)d_in[7];
  const float* ln_g      = (const float*)d_in[8];
  const float* ln_b      = (const float*)d_in[9];
  const int*   row       = (const int*)d_in[10];
  const int*   col       = (const int*)d_in[11];

  float* out      = (float*)d_out;
  float* out_feat = out;                           // [50000][128]
  float* out_vec  = out + (size_t)NATOMS * DIM;    // [50000][3][128]

  // workspace layout (16B-aligned sections)
  unsigned* qb  = (unsigned*)d_ws;                              // 50000*64 u32
  unsigned* kvb = qb + (size_t)NATOMS * 64;                     // 50000*128 u32
  unsigned short* mfeatb = (unsigned short*)(kvb + (size_t)NATOMS * 128); // 50000*128 bf16
  unsigned short* wTq = mfeatb + (size_t)NATOMS * 128;          // 384*128 bf16
  unsigned short* wTo = wTq + 384 * 128;                        // 128*128 bf16
  int4* descA  = (int4*)(wTo + 128 * 128);                      // 400000 int4
  float2* descB = (float2*)(descA + NEDGES);                    // 400000 float2
  int* cnt    = (int*)(descB + NEDGES);                         // 50000
  int* base   = cnt + NATOMS;                                   // 50001
  int* cursor = base + NATOMS + 1;                              // 50000
  int* locx   = cursor + NATOMS;                                // 50000
  int* psum   = locx + NATOMS;                                  // 256

  k_convert<<<256, 256, 0, stream>>>(qkv_w, out_w, wTq, wTo, cnt);

  k_ln_qkv_hist<<<LN_NB + HIST_NB, 256, 0, stream>>>(
      node_feat, wTq, qkv_b, ln_g, ln_b, qb, kvb, row, cnt);

  k_scan1<<<SCAN_NB, 256, 0, stream>>>(cnt, locx, psum);
  k_scan23<<<SCAN_NB, 256, 0, stream>>>(psum, locx, base, cursor);
  k_scatter<<<HIST_NB, 256, 0, stream>>>(row, col, radial, edge_vec, cursor,
                                         descA, descB);

  k_edge_csr<<<NATOMS / 4, 256, 0, stream>>>(
      qb, (const uint2*)kvb, (const float2*)edge_feat, descA, descB, base,
      (unsigned*)mfeatb, out_vec);

  k_out<<<NATOMS / 16, 256, 0, stream>>>(mfeatb, wTo, out_b, out_feat);
}